// Round 2
// baseline (6234.700 us; speedup 1.0000x reference)
//
#include <hip/hip_runtime.h>

#define AG __HIP_MEMORY_SCOPE_AGENT
#define B_ 16
#define T_ 512
#define P_ 2048
#define SN_ 256
#define SD_ 1024
#define NG 16                 // groups (ONE batch each)
#define GB 16                 // blocks per group (64 den cols each)
#define NBLK (NG * GB)        // 256 blocks = 256 CUs, num rides inside
#define NTHR 1024
#define CHU 80                // chunk stride in u64: 64 den words + 16 num words

typedef unsigned long long u64;

__device__ __forceinline__ float alf(const float* p){ return __hip_atomic_load(p, __ATOMIC_RELAXED, AG); }
__device__ __forceinline__ void  asf(float* p, float v){ __hip_atomic_store(p, v, __ATOMIC_RELAXED, AG); }
__device__ __forceinline__ void  rsu(unsigned* p, unsigned v){ __hip_atomic_store(p, v, __ATOMIC_RELEASE, AG); }
__device__ __forceinline__ u64   ald64(const u64* p){ return __hip_atomic_load(p, __ATOMIC_RELAXED, AG); }
__device__ __forceinline__ void  ast64(u64* p, u64 v){ __hip_atomic_store(p, v, __ATOMIC_RELAXED, AG); }
__device__ __forceinline__ u64   pk(float v, unsigned t){ return ((u64)t << 32) | (u64)__float_as_uint(v); }
__device__ __forceinline__ void wait_eq(unsigned* p, unsigned v){
  while (__hip_atomic_load(p, __ATOMIC_RELAXED, AG) != v) __builtin_amdgcn_s_sleep(1);
  asm volatile("" ::: "memory");
}

// Exp-space forward recursion, producer/consumer dataflow, ONE barrier/step.
// ROUND 11 restructure: 16 groups x 16 blocks, ONE batch per group -> all
// 256 CUs active (was 144), per-step den work per block HALVED:
//   - 64 fma/lane (was 128), 16 b128 LDS broadcasts/lane (was 32)
//   - chunk 80 words (was 130+), fold = 1 LDS read + 4 shfl (was 2+3)
// num (256 states) is a thin subnet distributed across the same blocks:
//   block (g,r) owns num cols [16r,16r+16) of batch g; wave wv contributes
//   k-slice [16wv,16wv+16) (4 fma/lane); wave15 folds+publishes post-barrier.
// M is now CONSUMER-side: every block computes max over staged chunk-0
// values (bit-identical across blocks -> consistent scale, zero comm).
// Tags are t+1 (zeroed ws tag 0 can never satisfy a poll -> no init race).
// 2-parity chunks/red/qn/Ms: full all-to-all coupling within a group means
// parity slots are only rewritten two steps later -> race-free w/ 1 barrier.
__global__ void __attribute__((amdgpu_flat_work_group_size(1024, 1024)))
__attribute__((amdgpu_waves_per_eu(4, 4))) lfmmi_kernel(
    const float* __restrict__ input, const int* __restrict__ seqlen,
    const float* __restrict__ num_init, const float* __restrict__ num_trans,
    const float* __restrict__ num_final, const int* __restrict__ num_pdf,
    const float* __restrict__ den_init, const float* __restrict__ den_trans,
    const float* __restrict__ den_final, const int* __restrict__ den_pdf,
    float* __restrict__ out, float* __restrict__ ws)
{
  __shared__ __align__(16) unsigned char smem[15872];
  // loop layout:
  float* qsW = (float*)smem;                 // [16][64]    4096 B
  float* red = (float*)(smem + 4096);        // [2][16][67] 8576 B -> 12672
  float* qn  = (float*)(smem + 12672);       // [2][256]    2048 B -> 14720
  float* rn  = (float*)(smem + 14720);       // [16][17]    1088 B -> 15808
  float* Ms  = (float*)(smem + 15808);       // [2]
  // epilogue reuse: qf = smem[0..4096), rs = smem[4096..8192)

  const int tid = threadIdx.x;
  const int bid = blockIdx.x;

  // workspace carve
  u64*      Qc     = (u64*)ws;                         // [2][NG][GB][CHU]
  float*    DenRes = (float*)(Qc + 2*NG*GB*CHU);       // [16]
  float*    NumRes = DenRes + 16;                      // [16]
  unsigned* DF     = (unsigned*)(NumRes + 16);         // [NG][16]
  unsigned* NF     = DF + NG*16;                       // [NG][16]

  const int g = bid >> 4, r = bid & 15;
  const int col0 = r * 64;
  const int wv = tid >> 6, ln = tid & 63;
  const int tm = ln >> 4, j16 = ln & 15;   // den fold team coords
  const int o  = 4 * wv + tm;              // den output this lane folds
  const bool lead = (j16 == 0);            // 4 leads per wave, 64 per block
  const bool nw = (wv == 15);              // num fold wave

  const int slen = seqlen[g];
  const size_t inb = (size_t)g * T_ * P_;

  // --- den W regs: wreg[j] = exp(trans[64*wv + j][col0 + ln]) ---
  float wreg[64];
  {
    const float* wb = den_trans + (size_t)(64 * wv) * SD_ + col0 + ln;
    #pragma unroll
    for (int j = 0; j < 64; ++j) wreg[j] = __expf(wb[(size_t)j * SD_]);
  }
  // --- num W regs: wn[j] = exp(ntrans[16*wv + 4*tm + j][16*r + j16]) ---
  float wn0, wn1, wn2, wn3;
  {
    const float* nb = num_trans + (size_t)(16 * wv + 4 * tm) * SN_ + 16 * r + j16;
    wn0 = __expf(nb[0]);      wn1 = __expf(nb[SN_]);
    wn2 = __expf(nb[2*SN_]);  wn3 = __expf(nb[3*SN_]);
  }

  int pdfc = 0, pdfn = 0;
  if (lead) pdfc = den_pdf[col0 + o];
  if (nw && ln < 16) pdfn = num_pdf[16 * r + ln];

  u64* myCh0 = Qc + ((size_t)(0 * NG + g) * GB + r) * CHU;
  u64* myCh1 = Qc + ((size_t)(1 * NG + g) * GB + r) * CHU;

  // --- init: publish q0 with tag 1 (tag 0 = zeroed ws, never matches) ---
  float v_prev = 0.f, v_pn = 0.f, Lr_d = 0.f, Lr_n = 0.f;
  if (lead) {
    v_prev = __expf(den_init[col0 + o] + input[inb + pdfc]);
    ast64(myCh0 + o, pk(v_prev, 1u));
  }
  if (nw && ln < 16) {
    v_pn = __expf(num_init[16 * r + ln] + input[inb + pdfn]);
    ast64(myCh0 + 64 + ln, pk(v_pn, 1u));
  }

  for (int t = 1; t <= 511; ++t) {
    const int pp = (t - 1) & 1, pc = t & 1;
    const unsigned et = (unsigned)t;      // tag of q_{t-1}
    // emission gathers issued early (hide under poll)
    float e = 0.f;
    if (lead) e = input[inb + (size_t)t * P_ + pdfc];
    float en = 0.f;
    if (nw && ln < 16) en = input[inb + (size_t)t * P_ + pdfn];

    // stage: wave wv polls chunk wv (64 den words; lanes<16 also 1 num word)
    {
      const u64* chs = Qc + ((size_t)(pp * NG + g) * GB + wv) * CHU;
      const u64* p0 = chs + ln;
      const bool pn = (ln < 16);
      const u64* p1 = chs + 64 + ln;
      u64 x0 = ald64(p0);
      u64 x1 = pn ? ald64(p1) : 0;
      while ((unsigned)(x0 >> 32) != et) x0 = ald64(p0);
      const float q0 = __uint_as_float((unsigned)x0);
      qsW[wv * 64 + ln] = q0;
      if (pn) {
        while ((unsigned)(x1 >> 32) != et) x1 = ald64(p1);
        qn[pp * 256 + 16 * wv + ln] = __uint_as_float((unsigned)x1);
      }
      // consumer-side den M: max over chunk-0 values (identical in every block)
      if (wv == 0) {
        float mx = q0;
        #pragma unroll
        for (int d = 1; d < 64; d <<= 1) mx = fmaxf(mx, __shfl_xor(mx, d));
        if (ln == 0) Ms[pp] = mx;
      }
    }

    // den partials: 64 fma over own k-slice (broadcast reads of own scratch)
    float a = 0.f;
    {
      const float* qp = qsW + wv * 64;
      #pragma unroll
      for (int jj = 0; jj < 16; ++jj) {
        const float4 f = *(const float4*)(qp + 4 * jj);
        a = fmaf(f.x, wreg[4*jj+0], a);
        a = fmaf(f.y, wreg[4*jj+1], a);
        a = fmaf(f.z, wreg[4*jj+2], a);
        a = fmaf(f.w, wreg[4*jj+3], a);
      }
    }
    // num partial: 4 fma on own-wave staged slice, fold 4 lanes -> rn
    float an;
    {
      const float4 fn = *(const float4*)(qn + pp * 256 + 16 * wv + 4 * tm);
      an = fn.x * wn0;
      an = fmaf(fn.y, wn1, an);
      an = fmaf(fn.z, wn2, an);
      an = fmaf(fn.w, wn3, an);
    }
    an += __shfl_xor(an, 16); an += __shfl_xor(an, 32);
    if (ln < 16) rn[wv * 17 + ln] = an;
    red[(pc * 16 + wv) * 67 + ln] = a;
    __syncthreads();   // the ONLY barrier per step

    // den fold: lane sums 16 wave-partials of output o via read + 4 shfl
    float acc = red[(pc * 16 + j16) * 67 + o];
    acc += __shfl_xor(acc, 1);
    acc += __shfl_xor(acc, 2);
    acc += __shfl_xor(acc, 4);
    acc += __shfl_xor(acc, 8);
    const float Mv = Ms[pp];
    u64* myCh = pc ? myCh1 : myCh0;
    if (lead) {
      if (t < slen) v_prev = (acc / Mv) * __expf(e);   // else frozen carry
      ast64(myCh + o, pk(v_prev, (unsigned)(t + 1)));
    }
    if (r == 0 && wv == 0 && ln == 0 && t < slen) Lr_d += __logf(Mv);

    // num fold (wave15, off the other waves' critical path)
    if (nw) {
      const float4 fm = *(const float4*)(qn + pp * 256 + 4 * ln);
      float mn = fmaxf(fmaxf(fm.x, fm.y), fmaxf(fm.z, fm.w));
      #pragma unroll
      for (int d = 1; d < 64; d <<= 1) mn = fmaxf(mn, __shfl_xor(mn, d));
      float s = rn[(4*tm+0)*17 + j16] + rn[(4*tm+1)*17 + j16]
              + rn[(4*tm+2)*17 + j16] + rn[(4*tm+3)*17 + j16];
      s += __shfl_xor(s, 16); s += __shfl_xor(s, 32);
      if (ln < 16) {
        if (t < slen) v_pn = (s / mn) * __expf(en);    // else frozen carry
        ast64(myCh + 64 + ln, pk(v_pn, (unsigned)(t + 1)));
      }
      if (r == 0 && ln == 0 && t < slen) Lr_n += __logf(mn);
    }
  }

  // --- epilogue: r==0 blocks reduce final q (tag 512, parity 1) ---
  __syncthreads();
  if (r == 0) {
    float* qf = (float*)smem;              // [1024]
    float* rs = (float*)(smem + 4096);     // [1024]
    {
      const u64* ch = Qc + ((size_t)(1 * NG + g) * GB + wv) * CHU;
      const u64* pq = ch + ln;
      u64 y = ald64(pq);
      while ((unsigned)(y >> 32) != 512u) y = ald64(pq);
      qf[wv * 64 + ln] = __uint_as_float((unsigned)y);
    }
    float sn = 0.f;
    if (nw) {  // num final: lane (tm,j16) polls chunk j16 words 64+4tm..+3
      const u64* chc = Qc + ((size_t)(1 * NG + g) * GB + j16) * CHU + 64 + 4 * tm;
      u64 z0 = ald64(chc + 0), z1 = ald64(chc + 1);
      u64 z2 = ald64(chc + 2), z3 = ald64(chc + 3);
      while ((unsigned)(z0 >> 32) != 512u) z0 = ald64(chc + 0);
      while ((unsigned)(z1 >> 32) != 512u) z1 = ald64(chc + 1);
      while ((unsigned)(z2 >> 32) != 512u) z2 = ald64(chc + 2);
      while ((unsigned)(z3 >> 32) != 512u) z3 = ald64(chc + 3);
      const int cb = 16 * j16 + 4 * tm;
      sn = __uint_as_float((unsigned)z0) * __expf(num_final[cb + 0])
         + __uint_as_float((unsigned)z1) * __expf(num_final[cb + 1])
         + __uint_as_float((unsigned)z2) * __expf(num_final[cb + 2])
         + __uint_as_float((unsigned)z3) * __expf(num_final[cb + 3]);
      #pragma unroll
      for (int d = 1; d < 64; d <<= 1) sn += __shfl_xor(sn, d);
    }
    __syncthreads();
    rs[tid] = qf[tid] * __expf(den_final[tid]);
    __syncthreads();
    for (int off = 512; off; off >>= 1) {
      if (tid < off) rs[tid] += rs[tid + off];
      __syncthreads();
    }
    if (nw && ln == 0) {
      asf(NumRes + g, Lr_n + __logf(sn));
      rsu(NF + g * 16, 0x600D0100u | (unsigned)g);
    }
    if (tid == 0) {
      asf(DenRes + g, Lr_d + __logf(rs[0]));
      rsu(DF + g * 16, 0x600D0000u | (unsigned)g);
      if (g == 0) {
        for (int g2 = 0; g2 < NG; ++g2) wait_eq(DF + g2 * 16, 0x600D0000u | (unsigned)g2);
        for (int g2 = 0; g2 < NG; ++g2) wait_eq(NF + g2 * 16, 0x600D0100u | (unsigned)g2);
        float sden = 0.f, snum = 0.f;
        for (int i = 0; i < 16; ++i) { sden += alf(DenRes + i); snum += alf(NumRes + i); }
        out[0] = -(snum - sden);
      }
    }
  }
}

extern "C" void kernel_launch(void* const* d_in, const int* in_sizes, int n_in,
                              void* d_out, int out_size, void* d_ws, size_t ws_size,
                              hipStream_t stream) {
  const float* input     = (const float*)d_in[0];
  const int*   seqlen    = (const int*)  d_in[1];
  const float* num_init  = (const float*)d_in[2];
  const float* num_trans = (const float*)d_in[3];
  const float* num_final = (const float*)d_in[4];
  const int*   num_pdf   = (const int*)  d_in[5];
  const float* den_init  = (const float*)d_in[6];
  const float* den_trans = (const float*)d_in[7];
  const float* den_final = (const float*)d_in[8];
  const int*   den_pdf   = (const int*)  d_in[9];
  float* out = (float*)d_out;
  float* ws  = (float*)d_ws;   // ~330 KB used (tagged chunks + results + flags)

  void* args[] = { &input, &seqlen, &num_init, &num_trans, &num_final, &num_pdf,
                   &den_init, &den_trans, &den_final, &den_pdf, &out, &ws };
  hipLaunchCooperativeKernel((void*)lfmmi_kernel, dim3(NBLK), dim3(NTHR),
                             args, 0, stream);
}

// Round 6
// 1581.752 us; speedup vs baseline: 3.9416x; 3.9416x over previous
//
#include <hip/hip_runtime.h>

#define AG __HIP_MEMORY_SCOPE_AGENT
#define B_ 16
#define T_ 512
#define P_ 2048
#define SN_ 256
#define SD_ 1024
#define NG 16                 // den groups: one batch each
#define GB 16                 // blocks per group (64 cols each)
#define NBD (NG * GB)         // 256 den blocks
#define NBLK (NBD + B_)       // + 16 num blocks = 272
#define NTHR 1024
#define CHU 80                // chunk stride in u64: 64 q words + 1 M + pad (640B = 5 lines)

typedef unsigned long long u64;

__device__ __forceinline__ float alf(const float* p){ return __hip_atomic_load(p, __ATOMIC_RELAXED, AG); }
__device__ __forceinline__ void  asf(float* p, float v){ __hip_atomic_store(p, v, __ATOMIC_RELAXED, AG); }
__device__ __forceinline__ void  rsu(unsigned* p, unsigned v){ __hip_atomic_store(p, v, __ATOMIC_RELEASE, AG); }
__device__ __forceinline__ u64   ald64(const u64* p){ return __hip_atomic_load(p, __ATOMIC_RELAXED, AG); }
__device__ __forceinline__ void  ast64(u64* p, u64 v){ __hip_atomic_store(p, v, __ATOMIC_RELAXED, AG); }
__device__ __forceinline__ u64   pk(float v, unsigned t){ return ((u64)t << 32) | (u64)__float_as_uint(v); }
__device__ __forceinline__ void wait_eq(unsigned* p, unsigned v){
  while (__hip_atomic_load(p, __ATOMIC_RELAXED, AG) != v) __builtin_amdgcn_s_sleep(1);
  asm volatile("" ::: "memory");
}

// Exp-space forward recursion, producer/consumer dataflow, ONE barrier/step.
// ROUND 6 = round-5 structure with a LEGAL launch:
//  * den spread 2x vs round-1: 16 groups x 16 blocks, ONE batch per group ->
//    64 FMA/lane/step, 16 broadcast b128/lane, 1 poll word/lane, fold =
//    1 LDS read + 4 shfl. num stays in 16 DEDICATED block-local blocks.
//  * PLAIN launch (272 blocks > 256-CU cooperative capacity at 16 waves;
//    round-5's cooperative launch was validated-and-rejected -> out stayed 0).
//    Deadlock-free on any dispatch order: num blocks are block-local and
//    complete unconditionally, freeing CUs for queued den blocks; the den
//    all-to-all only needs den peers; the single aggregator block waits on
//    NF flags last, after 255 den blocks have exited.
//  * waves_per_eu(4,4) (round-1-proven; compiled to 60 VGPR there).
// Tags are t+1: zeroed/poisoned ws can never satisfy a poll; within a run,
// per-word tags are monotone, so a residual tag is always overwritten by a
// fresh smaller tag before the consumer expects it (audited r5).
// Race-freedom (ONE barrier/step, 2-parity slots): a block at stage(t+2)
// consumed tag-(t+2) words of ALL group chunks => every member completed
// fold(t+1) => passed stage(t+1); so no consumer still polls the parity
// slot being overwritten. LDS red/Ms parity slots safe by barrier
// transitivity block-locally.
__global__ void __attribute__((amdgpu_flat_work_group_size(1024, 1024)))
__attribute__((amdgpu_waves_per_eu(4, 4))) lfmmi_kernel(
    const float* __restrict__ input, const int* __restrict__ seqlen,
    const float* __restrict__ num_init, const float* __restrict__ num_trans,
    const float* __restrict__ num_final, const int* __restrict__ num_pdf,
    const float* __restrict__ den_init, const float* __restrict__ den_trans,
    const float* __restrict__ den_final, const int* __restrict__ den_pdf,
    float* __restrict__ out, float* __restrict__ ws)
{
  __shared__ __align__(16) unsigned char smem[18464];
  const int tid = threadIdx.x;
  const int bid = blockIdx.x;

  // workspace carve
  u64*      Qc     = (u64*)ws;                         // [2][NG][GB][CHU]
  float*    DenRes = (float*)(Qc + 2*NG*GB*CHU);       // [16]
  float*    NumRes = DenRes + 16;                      // [16]
  unsigned* DF     = (unsigned*)(NumRes + 16);         // [NG][16]
  unsigned* NF     = DF + NG*16;                       // [16][16]

  const int wv = tid >> 6, ln = tid & 63;

  if (bid < NBD) {
    // ================= DEN =================
    const int g = bid >> 4, r = bid & 15;
    const int col0 = r * 64;
    const int tm = ln >> 4, j16 = ln & 15;   // team (output-in-wave), lane-in-team
    const int o  = 4 * wv + tm;              // output (local col) this lane folds
    const bool lead = (j16 == 0);            // 4 leads/wave, 64/block

    float* qsW = (float*)smem;               // [16][64]    4 KB
    float* red = (float*)(smem + 4096);      // [2][16][67] 8576 B -> 12672
    float* Ms  = (float*)(smem + 12672);     // [2]

    // --- W regs: wreg[j] = exp(trans[64*wv + j][col0 + ln]) ---
    float wreg[64];
    {
      const float* wb = den_trans + (size_t)(64 * wv) * SD_ + col0 + ln;
      #pragma unroll
      for (int j = 0; j < 64; ++j) wreg[j] = __expf(wb[(size_t)j * SD_]);
    }

    const int slen = seqlen[g];
    const size_t inb = (size_t)g * T_ * P_;
    int pdfc = 0;
    if (lead) pdfc = den_pdf[col0 + o];

    u64* myCh0 = Qc + ((size_t)(0 * NG + g) * GB + r) * CHU;
    u64* myCh1 = Qc + ((size_t)(1 * NG + g) * GB + r) * CHU;

    // --- init: publish q0 with tag 1 (residual/poison never matches) ---
    float v_prev = 0.f, Lr = 0.f;
    if (lead) {
      v_prev = __expf(den_init[col0 + o] + input[inb + pdfc]);
      ast64(myCh0 + o, pk(v_prev, 1u));
    }
    if (r == 0 && wv == 0) {   // M = max over outputs 0..3 (fixed subset, valid scale)
      float mx = lead ? v_prev : 0.f;
      #pragma unroll
      for (int d = 1; d < 64; d <<= 1) mx = fmaxf(mx, __shfl_xor(mx, d));
      if (ln == 0) ast64(myCh0 + 64, pk(mx, 1u));
    }

    for (int t = 1; t <= 511; ++t) {
      const int pp = (t - 1) & 1, pc = t & 1;
      const unsigned et = (unsigned)t;       // tag of q_{t-1}
      // lead: prefetch emission gather (hidden behind the poll)
      float e = 0.f;
      if (lead) e = input[inb + (size_t)t * P_ + pdfc];

      // stage: wave wv polls chunk wv (1 q word/lane; wave0 lane0 also M).
      // Both loads issued before any spin; retry only stale words.
      {
        const u64* chs = Qc + ((size_t)(pp * NG + g) * GB + wv) * CHU;
        const u64* p0 = chs + ln;
        const bool pm = (wv == 0 && ln == 0);
        const u64* pM = chs + 64;
        u64 x0 = ald64(p0);
        u64 xm = pm ? ald64(pM) : 0;
        while ((unsigned)(x0 >> 32) != et) x0 = ald64(p0);
        qsW[wv * 64 + ln] = __uint_as_float((unsigned)x0);
        if (pm) {
          while ((unsigned)(xm >> 32) != et) xm = ald64(pM);
          Ms[pp] = __uint_as_float((unsigned)xm);
        }
      }
      // partials for all 64 outputs over own k-slice (broadcast reads)
      float a = 0.f;
      {
        const float* qp = qsW + wv * 64;
        #pragma unroll
        for (int jj = 0; jj < 16; ++jj) {
          const float4 f = *(const float4*)(qp + 4 * jj);
          a = fmaf(f.x, wreg[4*jj+0], a);
          a = fmaf(f.y, wreg[4*jj+1], a);
          a = fmaf(f.z, wreg[4*jj+2], a);
          a = fmaf(f.w, wreg[4*jj+3], a);
        }
      }
      red[(pc * 16 + wv) * 67 + ln] = a;
      __syncthreads();   // the ONLY barrier per step

      // fold: lane sums the 16 wave-partials of output o (1 read + 4 shfl)
      float acc = red[(pc * 16 + j16) * 67 + o];
      acc += __shfl_xor(acc, 1);
      acc += __shfl_xor(acc, 2);
      acc += __shfl_xor(acc, 4);
      acc += __shfl_xor(acc, 8);
      const float Mv = Ms[pp];
      u64* myCh = pc ? myCh1 : myCh0;
      if (lead) {
        if (t < slen) v_prev = (acc / Mv) * __expf(e);   // else frozen carry
        ast64(myCh + o, pk(v_prev, (unsigned)(t + 1)));
      }
      if (r == 0 && wv == 0) {
        float mx = lead ? v_prev : 0.f;
        #pragma unroll
        for (int d = 1; d < 64; d <<= 1) mx = fmaxf(mx, __shfl_xor(mx, d));
        if (ln == 0) {
          ast64(myCh + 64, pk(mx, (unsigned)(t + 1)));
          if (t < slen) Lr += __logf(Mv);
        }
      }
    }

    // --- epilogue: r==0 blocks reduce final q (tag 512, parity 1) ---
    if (r == 0) {
      __syncthreads();
      float* qf = (float*)smem;              // [1024]
      float* rs = (float*)(smem + 4096);     // [1024]
      {
        const u64* pq = Qc + ((size_t)(1 * NG + g) * GB + wv) * CHU + ln;
        u64 y = ald64(pq);
        while ((unsigned)(y >> 32) != 512u) y = ald64(pq);
        qf[wv * 64 + ln] = __uint_as_float((unsigned)y);
      }
      __syncthreads();
      rs[tid] = qf[tid] * __expf(den_final[tid]);
      __syncthreads();
      for (int off = 512; off; off >>= 1) {
        if (tid < off) rs[tid] += rs[tid + off];
        __syncthreads();
      }
      if (tid == 0) {
        asf(DenRes + g, Lr + __logf(rs[0]));
        rsu(DF + g * 16, 0x600D0000u | (unsigned)g);
        if (g == 0) {
          for (int g2 = 0; g2 < NG; ++g2) wait_eq(DF + g2 * 16, 0x600D0000u | (unsigned)g2);
          for (int b2 = 0; b2 < B_; ++b2)  wait_eq(NF + b2 * 16, 0x600D0100u | (unsigned)b2);
          float sden = 0.f, snum = 0.f;
          for (int i = 0; i < 16; ++i) { sden += alf(DenRes + i); snum += alf(NumRes + i); }
          out[0] = -(snum - sden);
        }
      }
    }
  } else {
    // ================= NUM (fully block-local, round-1 verbatim) =================
    const int b = bid - NBD;
    float* qn   = (float*)smem;               // [2][256] 2 KB
    float* redn = (float*)(smem + 2048);      // [16][256] 16 KB
    float* Ms2  = (float*)(smem + 18432);     // [2]
    const size_t inb = (size_t)b * T_ * P_;
    const int slen = seqlen[b];

    float wn[64];
    {
      const float* wb = num_trans + (size_t)(wv * 16) * SN_ + ln;
      #pragma unroll
      for (int kk = 0; kk < 16; ++kk) {
        #pragma unroll
        for (int cc = 0; cc < 4; ++cc)
          wn[kk * 4 + cc] = __expf(wb[(size_t)kk * SN_ + 64 * cc]);
      }
    }
    int pdfn[4] = {0, 0, 0, 0};
    float Lr = 0.f;
    if (wv == 0) {
      #pragma unroll
      for (int cc = 0; cc < 4; ++cc) pdfn[cc] = num_pdf[ln + 64 * cc];
      float mx = 0.f;
      #pragma unroll
      for (int cc = 0; cc < 4; ++cc) {
        const float v = __expf(num_init[ln + 64 * cc] + input[inb + pdfn[cc]]);
        qn[ln + 64 * cc] = v;
        mx = fmaxf(mx, v);
      }
      #pragma unroll
      for (int d = 1; d < 64; d <<= 1) mx = fmaxf(mx, __shfl_xor(mx, d));
      if (ln == 0) Ms2[0] = mx;
    }
    __syncthreads();

    int tlast = 0;
    for (int t = 1; t <= 511; ++t) {
      if (t >= slen) break;
      tlast = t;
      const int pr = (t - 1) & 1, pw = t & 1;
      float e[4] = {0.f, 0.f, 0.f, 0.f};
      if (wv == 0) {
        #pragma unroll
        for (int cc = 0; cc < 4; ++cc) e[cc] = input[inb + (size_t)t * P_ + pdfn[cc]];
      }
      const float* qp = qn + pr * 256 + wv * 16;
      float ac[4] = {0.f, 0.f, 0.f, 0.f};
      #pragma unroll
      for (int jj = 0; jj < 4; ++jj) {
        const float4 f = *(const float4*)(qp + 4 * jj);
        #pragma unroll
        for (int cc = 0; cc < 4; ++cc) {
          ac[cc] = fmaf(f.x, wn[(4*jj+0)*4+cc], ac[cc]);
          ac[cc] = fmaf(f.y, wn[(4*jj+1)*4+cc], ac[cc]);
          ac[cc] = fmaf(f.z, wn[(4*jj+2)*4+cc], ac[cc]);
          ac[cc] = fmaf(f.w, wn[(4*jj+3)*4+cc], ac[cc]);
        }
      }
      #pragma unroll
      for (int cc = 0; cc < 4; ++cc) redn[wv * 256 + cc * 64 + ln] = ac[cc];
      __syncthreads();
      if (wv == 0) {
        float acc[4] = {0.f, 0.f, 0.f, 0.f};
        #pragma unroll
        for (int w = 0; w < 16; ++w) {
          #pragma unroll
          for (int cc = 0; cc < 4; ++cc) acc[cc] += redn[w * 256 + cc * 64 + ln];
        }
        const float Mv = Ms2[pr];
        const float rM = 1.0f / Mv;
        float mx = 0.f;
        #pragma unroll
        for (int cc = 0; cc < 4; ++cc) {
          const float v = acc[cc] * rM * __expf(e[cc]);
          qn[pw * 256 + ln + 64 * cc] = v;
          mx = fmaxf(mx, v);
        }
        #pragma unroll
        for (int d = 1; d < 64; d <<= 1) mx = fmaxf(mx, __shfl_xor(mx, d));
        if (ln == 0) { Ms2[pw] = mx; Lr += __logf(Mv); }
      }
      __syncthreads();
    }
    const int cur = tlast & 1;
    if (wv == 0) {
      float s = 0.f;
      #pragma unroll
      for (int cc = 0; cc < 4; ++cc)
        s += qn[cur * 256 + ln + 64 * cc] * __expf(num_final[ln + 64 * cc]);
      #pragma unroll
      for (int d = 1; d < 64; d <<= 1) s += __shfl_xor(s, d);
      if (ln == 0) {
        asf(NumRes + b, Lr + __logf(s));
        rsu(NF + b * 16, 0x600D0100u | (unsigned)b);
      }
    }
  }
}

extern "C" void kernel_launch(void* const* d_in, const int* in_sizes, int n_in,
                              void* d_out, int out_size, void* d_ws, size_t ws_size,
                              hipStream_t stream) {
  const float* input     = (const float*)d_in[0];
  const int*   seqlen    = (const int*)  d_in[1];
  const float* num_init  = (const float*)d_in[2];
  const float* num_trans = (const float*)d_in[3];
  const float* num_final = (const float*)d_in[4];
  const int*   num_pdf   = (const int*)  d_in[5];
  const float* den_init  = (const float*)d_in[6];
  const float* den_trans = (const float*)d_in[7];
  const float* den_final = (const float*)d_in[8];
  const int*   den_pdf   = (const int*)  d_in[9];
  float* out = (float*)d_out;
  float* ws  = (float*)d_ws;   // ~332 KB used (tagged chunks + results + flags)

  // PLAIN launch (272 blocks exceeds cooperative co-residency capacity at
  // 16 waves/block; deadlock-freedom on any dispatch order argued in the
  // kernel comment: num blocks are block-local and always completable).
  lfmmi_kernel<<<dim3(NBLK), dim3(NTHR), 0, stream>>>(
      input, seqlen, num_init, num_trans, num_final, num_pdf,
      den_init, den_trans, den_final, den_pdf, out, ws);
}

// Round 7
// 1286.944 us; speedup vs baseline: 4.8446x; 1.2291x over previous
//
#include <hip/hip_runtime.h>

#define AG __HIP_MEMORY_SCOPE_AGENT
#define B_ 16
#define T_ 512
#define P_ 2048
#define SN_ 256
#define SD_ 1024
#define NGD 8                 // den groups (one b-pair each)
#define GB 16                 // blocks per den group (64 cols each)
#define NBD (NGD * GB)        // 128 den blocks
#define NBLK (NBD + B_)       // + 16 num blocks = 144
#define NTHR 1024
#define CHU 136               // chunk stride in u64 (64 b0 + 64 b1 + 2 M + pad)

typedef unsigned long long u64;

__device__ __forceinline__ float alf(const float* p){ return __hip_atomic_load(p, __ATOMIC_RELAXED, AG); }
__device__ __forceinline__ void  asf(float* p, float v){ __hip_atomic_store(p, v, __ATOMIC_RELAXED, AG); }
__device__ __forceinline__ u64   ald64(const u64* p){ return __hip_atomic_load(p, __ATOMIC_RELAXED, AG); }
// ROUND 7: publishes use atomic EXCHANGE, not atomic store. A relaxed
// global store can linger in the CU write-coalescing buffer (nothing forces
// it out; the producer immediately enters its next poll spin), so consumers
// burn ~900cy retry rounds against a store that hasn't reached the LLC.
// An RMW atomic executes AT the coherence point on issue -- prompt
// visibility, no producer stall (result discarded).
__device__ __forceinline__ void  axg64(u64* p, u64 v){
  (void)__hip_atomic_exchange(p, v, __ATOMIC_RELAXED, AG);
}
__device__ __forceinline__ void  rxu(unsigned* p, unsigned v){
  (void)__hip_atomic_exchange(p, v, __ATOMIC_RELEASE, AG);
}
__device__ __forceinline__ u64   pk(float v, unsigned t){ return ((u64)t << 32) | (u64)__float_as_uint(v); }
__device__ __forceinline__ void wait_eq(unsigned* p, unsigned v){
  while (__hip_atomic_load(p, __ATOMIC_RELAXED, AG) != v) __builtin_amdgcn_s_sleep(1);
  asm volatile("" ::: "memory");
}

// Exp-space forward recursion, producer/consumer dataflow, ONE barrier/step:
//   q_t[b,c] = (sum_k q_{t-1}[b,k] * W[k,c]) / M[b] * exp(e_t[b,c])
// den: 8 groups x 16 blocks; group owns b-pair {2g,2g+1}; block owns 64 cols.
// Structure = round-1 verbatim (measured 1282us): parallel-issued polls,
// private LDS scratch per wave, ONE barrier/step, 8-lane fold teams,
// producer-side M, frozen carry in lead register, 2-parity slots.
// ROUND 7 single change: publish path store -> atomic exchange (see axg64).
// Evidence: r6 halved per-lane FMA yet step time was unchanged => step is
// ~90% communication latency V; WC-buffer lingering of the publish store is
// the only V-component large enough to explain ~2us.
__global__ void __attribute__((amdgpu_flat_work_group_size(1024, 1024)))
__attribute__((amdgpu_waves_per_eu(4, 4))) lfmmi_kernel(
    const float* __restrict__ input, const int* __restrict__ seqlen,
    const float* __restrict__ num_init, const float* __restrict__ num_trans,
    const float* __restrict__ num_final, const int* __restrict__ num_pdf,
    const float* __restrict__ den_init, const float* __restrict__ den_trans,
    const float* __restrict__ den_final, const int* __restrict__ den_pdf,
    float* __restrict__ out, float* __restrict__ ws)
{
  __shared__ __align__(16) unsigned char smem[25248];
  const int tid = threadIdx.x;
  const int bid = blockIdx.x;

  // workspace carve
  u64*      Qc     = (u64*)ws;                         // [2][NGD][GB][CHU]
  float*    DenRes = (float*)(Qc + 2*NGD*GB*CHU);      // [16]
  float*    NumRes = DenRes + 16;                      // [16]
  unsigned* DF     = (unsigned*)(NumRes + 16);         // [NGD][16]
  unsigned* NF     = DF + NGD*16;                      // [16][16]

  const int wv = tid >> 6, ln = tid & 63;

  if (bid < NBD) {
    // ================= DEN =================
    const int g = bid >> 4, r = bid & 15;
    const int col0 = r * 64;
    const int tm = ln >> 3, j8 = ln & 7;     // team, lane-in-team
    const int o  = 8 * wv + tm;              // output index this team folds
    const int ob = o >> 6, oc = o & 63;      // batch-half, column of output
    const bool lead = (j8 == 0);

    float* qsW = (float*)smem;               // [16][136] per-wave scratch
    float* red = (float*)(smem + 8704);      // [2][16][129] partials
    float* Ms  = (float*)(smem + 25216);     // [2][2] (parity, b)

    // --- W regs: wreg[j] = exp(trans[64*wv + j][col0 + ln]) ---
    float wreg[64];
    {
      const float* wb = den_trans + (size_t)(64 * wv) * SD_ + col0 + ln;
      #pragma unroll
      for (int j = 0; j < 64; ++j) wreg[j] = __expf(wb[(size_t)j * SD_]);
    }

    const int b0 = 2 * g, b1 = 2 * g + 1;
    const size_t inb0 = (size_t)b0 * T_ * P_, inb1 = (size_t)b1 * T_ * P_;
    int pdfc = 0, slenL = 0; size_t inbL = 0;
    if (lead) {
      pdfc  = den_pdf[col0 + oc];
      inbL  = ob ? inb1 : inb0;
      slenL = seqlen[ob ? b1 : b0];
    }
    u64* myCh0 = Qc + ((size_t)(0 * NGD + g) * GB + r) * CHU;
    u64* myCh1 = Qc + ((size_t)(1 * NGD + g) * GB + r) * CHU;

    // --- init: every team lead computes + publishes its own q0 (tag 0) ---
    float v_prev = 0.f, Lr = 0.f;
    if (lead) {
      v_prev = __expf(den_init[col0 + oc] + input[inbL + pdfc]);
      axg64(myCh0 + o, pk(v_prev, 0u));
    }
    if (r == 0 && (wv == 0 || wv == 8)) {     // M0 from wave0 (b0), M1 from wave8 (b1)
      float mx = lead ? v_prev : 0.f;
      #pragma unroll
      for (int d = 1; d < 64; d <<= 1) mx = fmaxf(mx, __shfl_xor(mx, d));
      if (ln == 0) axg64(myCh0 + 128 + ob, pk(mx, 0u));
    }

    for (int t = 1; t <= 511; ++t) {
      const int pp = (t - 1) & 1, pc = t & 1;
      const unsigned et = (unsigned)(t - 1);
      // lead: prefetch emission gather (hidden behind the poll)
      float e = 0.f;
      if (lead) e = input[inbL + (size_t)t * P_ + pdfc];

      // stage: wave wv polls its producer's chunk into private scratch.
      // ALL poll loads issued in parallel before any wait; retry only
      // stale streams.
      {
        const u64* chs = Qc + ((size_t)(pp * NGD + g) * GB + wv) * CHU;
        const u64* p0 = chs + ln;
        const u64* p1 = chs + 64 + ln;
        const bool pm = (wv == 0 && ln < 2);
        const u64* p2 = chs + 128 + ln;     // only dereferenced when pm
        u64 x0 = ald64(p0);
        u64 x1 = ald64(p1);
        u64 x2 = pm ? ald64(p2) : 0;
        while ((unsigned)(x0 >> 32) != et) x0 = ald64(p0);
        qsW[wv * 136 + ln] = __uint_as_float((unsigned)x0);
        while ((unsigned)(x1 >> 32) != et) x1 = ald64(p1);
        qsW[wv * 136 + 64 + ln] = __uint_as_float((unsigned)x1);
        if (pm) {
          while ((unsigned)(x2 >> 32) != et) x2 = ald64(p2);
          Ms[pp * 2 + ln] = __uint_as_float((unsigned)x2);
        }
      }
      // compute partials for all 128 outputs over own k-slice (broadcast reads)
      float a0 = 0.f, a1 = 0.f;
      {
        const float* qp = qsW + wv * 136;
        #pragma unroll
        for (int jj = 0; jj < 16; ++jj) {
          const float4 f0 = *(const float4*)(qp + 4 * jj);
          const float4 f1 = *(const float4*)(qp + 64 + 4 * jj);
          a0 = fmaf(f0.x, wreg[4*jj+0], a0); a0 = fmaf(f0.y, wreg[4*jj+1], a0);
          a0 = fmaf(f0.z, wreg[4*jj+2], a0); a0 = fmaf(f0.w, wreg[4*jj+3], a0);
          a1 = fmaf(f1.x, wreg[4*jj+0], a1); a1 = fmaf(f1.y, wreg[4*jj+1], a1);
          a1 = fmaf(f1.z, wreg[4*jj+2], a1); a1 = fmaf(f1.w, wreg[4*jj+3], a1);
        }
      }
      red[(pc * 16 + wv) * 129 + ln]      = a0;   // output o=ln   (b0)
      red[(pc * 16 + wv) * 129 + 64 + ln] = a1;   // output o=64+ln (b1)
      __syncthreads();   // the ONLY barrier per step

      // fold: team folds output o; lead scales + publishes
      float acc = red[(pc * 16 + 2 * j8) * 129 + o]
                + red[(pc * 16 + 2 * j8 + 1) * 129 + o];
      acc += __shfl_xor(acc, 1);
      acc += __shfl_xor(acc, 2);
      acc += __shfl_xor(acc, 4);
      u64* myCh = pc ? myCh1 : myCh0;
      if (lead) {
        const float Mv = Ms[pp * 2 + ob];
        if (t < slenL) v_prev = (acc / Mv) * __expf(e);   // else frozen carry
        axg64(myCh + o, pk(v_prev, (unsigned)t));
      }
      if (r == 0 && (wv == 0 || wv == 8)) {
        float mx = lead ? v_prev : 0.f;
        #pragma unroll
        for (int d = 1; d < 64; d <<= 1) mx = fmaxf(mx, __shfl_xor(mx, d));
        if (ln == 0) {
          axg64(myCh + 128 + ob, pk(mx, (unsigned)t));
          if (t < slenL) Lr += __logf(Ms[pp * 2 + ob]);   // lane0: lead of o=0/64
        }
      }
    }

    // --- epilogue: r==0 blocks reduce final q (t=511, parity 1) ---
    if (r == 0) {
      __syncthreads();
      float* qf = (float*)smem;               // [2][1024]
      float* rs = (float*)(smem + 8192);      // [1024] x2 halves (ends 16384 < red[1] base)
      {
        const u64* ch = Qc + ((size_t)(1 * NGD + g) * GB + wv) * CHU;
        const u64* p0 = ch + ln;
        const u64* p1 = ch + 64 + ln;
        u64 y0 = ald64(p0);
        u64 y1 = ald64(p1);
        while ((unsigned)(y0 >> 32) != 511u) y0 = ald64(p0);
        while ((unsigned)(y1 >> 32) != 511u) y1 = ald64(p1);
        qf[wv * 64 + ln]        = __uint_as_float((unsigned)y0);
        qf[1024 + wv * 64 + ln] = __uint_as_float((unsigned)y1);
      }
      __syncthreads();
      const int b2e = tid >> 9, ce = tid & 511;
      rs[tid] = qf[b2e * 1024 + ce] * __expf(den_final[ce])
              + qf[b2e * 1024 + 512 + ce] * __expf(den_final[512 + ce]);
      __syncthreads();
      for (int off = 256; off; off >>= 1) {
        const int base = (tid >= 512) ? 512 : 0, i = tid - base;
        if (i < off) rs[base + i] += rs[base + i + off];
        __syncthreads();
      }
      if (tid == 0)   asf(DenRes + 2 * g,     Lr + __logf(rs[0]));     // wave0 lane0: Lr(b0)
      if (tid == 512) asf(DenRes + 2 * g + 1, Lr + __logf(rs[512]));   // wave8 lane0: Lr(b1)
      __syncthreads();
      if (tid == 0) {
        rxu(DF + g * 16, 0x600D0000u | (unsigned)g);
        if (g == 0) {
          for (int g2 = 0; g2 < NGD; ++g2) wait_eq(DF + g2 * 16, 0x600D0000u | (unsigned)g2);
          for (int b2 = 0; b2 < B_; ++b2)  wait_eq(NF + b2 * 16, 0x600D0100u | (unsigned)b2);
          float sden = 0.f, snum = 0.f;
          for (int i = 0; i < 16; ++i) { sden += alf(DenRes + i); snum += alf(NumRes + i); }
          out[0] = -(snum - sden);
        }
      }
    }
  } else {
    // ================= NUM (fully block-local, round-1 verbatim) =================
    const int b = bid - NBD;
    float* qn   = (float*)smem;               // [2][256] 2 KB
    float* redn = (float*)(smem + 2048);      // [16][256] 16 KB
    float* Ms2  = (float*)(smem + 18432);     // [2]
    const size_t inb = (size_t)b * T_ * P_;
    const int slen = seqlen[b];

    float wn[64];
    {
      const float* wb = num_trans + (size_t)(wv * 16) * SN_ + ln;
      #pragma unroll
      for (int kk = 0; kk < 16; ++kk) {
        #pragma unroll
        for (int cc = 0; cc < 4; ++cc)
          wn[kk * 4 + cc] = __expf(wb[(size_t)kk * SN_ + 64 * cc]);
      }
    }
    int pdfn[4] = {0, 0, 0, 0};
    float Lr = 0.f;
    if (wv == 0) {
      #pragma unroll
      for (int cc = 0; cc < 4; ++cc) pdfn[cc] = num_pdf[ln + 64 * cc];
      float mx = 0.f;
      #pragma unroll
      for (int cc = 0; cc < 4; ++cc) {
        const float v = __expf(num_init[ln + 64 * cc] + input[inb + pdfn[cc]]);
        qn[ln + 64 * cc] = v;
        mx = fmaxf(mx, v);
      }
      #pragma unroll
      for (int d = 1; d < 64; d <<= 1) mx = fmaxf(mx, __shfl_xor(mx, d));
      if (ln == 0) Ms2[0] = mx;
    }
    __syncthreads();

    int tlast = 0;
    for (int t = 1; t <= 511; ++t) {
      if (t >= slen) break;
      tlast = t;
      const int pr = (t - 1) & 1, pw = t & 1;
      float e[4] = {0.f, 0.f, 0.f, 0.f};
      if (wv == 0) {
        #pragma unroll
        for (int cc = 0; cc < 4; ++cc) e[cc] = input[inb + (size_t)t * P_ + pdfn[cc]];
      }
      const float* qp = qn + pr * 256 + wv * 16;
      float ac[4] = {0.f, 0.f, 0.f, 0.f};
      #pragma unroll
      for (int jj = 0; jj < 4; ++jj) {
        const float4 f = *(const float4*)(qp + 4 * jj);
        #pragma unroll
        for (int cc = 0; cc < 4; ++cc) {
          ac[cc] = fmaf(f.x, wn[(4*jj+0)*4+cc], ac[cc]);
          ac[cc] = fmaf(f.y, wn[(4*jj+1)*4+cc], ac[cc]);
          ac[cc] = fmaf(f.z, wn[(4*jj+2)*4+cc], ac[cc]);
          ac[cc] = fmaf(f.w, wn[(4*jj+3)*4+cc], ac[cc]);
        }
      }
      #pragma unroll
      for (int cc = 0; cc < 4; ++cc) redn[wv * 256 + cc * 64 + ln] = ac[cc];
      __syncthreads();
      if (wv == 0) {
        float acc[4] = {0.f, 0.f, 0.f, 0.f};
        #pragma unroll
        for (int w = 0; w < 16; ++w) {
          #pragma unroll
          for (int cc = 0; cc < 4; ++cc) acc[cc] += redn[w * 256 + cc * 64 + ln];
        }
        const float Mv = Ms2[pr];
        const float rM = 1.0f / Mv;
        float mx = 0.f;
        #pragma unroll
        for (int cc = 0; cc < 4; ++cc) {
          const float v = acc[cc] * rM * __expf(e[cc]);
          qn[pw * 256 + ln + 64 * cc] = v;
          mx = fmaxf(mx, v);
        }
        #pragma unroll
        for (int d = 1; d < 64; d <<= 1) mx = fmaxf(mx, __shfl_xor(mx, d));
        if (ln == 0) { Ms2[pw] = mx; Lr += __logf(Mv); }
      }
      __syncthreads();
    }
    const int cur = tlast & 1;
    if (wv == 0) {
      float s = 0.f;
      #pragma unroll
      for (int cc = 0; cc < 4; ++cc)
        s += qn[cur * 256 + ln + 64 * cc] * __expf(num_final[ln + 64 * cc]);
      #pragma unroll
      for (int d = 1; d < 64; d <<= 1) s += __shfl_xor(s, d);
      if (ln == 0) {
        asf(NumRes + b, Lr + __logf(s));
        rxu(NF + b * 16, 0x600D0100u | (unsigned)b);
      }
    }
  }
}

extern "C" void kernel_launch(void* const* d_in, const int* in_sizes, int n_in,
                              void* d_out, int out_size, void* d_ws, size_t ws_size,
                              hipStream_t stream) {
  const float* input     = (const float*)d_in[0];
  const int*   seqlen    = (const int*)  d_in[1];
  const float* num_init  = (const float*)d_in[2];
  const float* num_trans = (const float*)d_in[3];
  const float* num_final = (const float*)d_in[4];
  const int*   num_pdf   = (const int*)  d_in[5];
  const float* den_init  = (const float*)d_in[6];
  const float* den_trans = (const float*)d_in[7];
  const float* den_final = (const float*)d_in[8];
  const int*   den_pdf   = (const int*)  d_in[9];
  float* out = (float*)d_out;
  float* ws  = (float*)d_ws;   // ~280 KB used (tagged chunks + results + flags)

  void* args[] = { &input, &seqlen, &num_init, &num_trans, &num_final, &num_pdf,
                   &den_init, &den_trans, &den_final, &den_pdf, &out, &ws };
  hipLaunchCooperativeKernel((void*)lfmmi_kernel, dim3(NBLK), dim3(NTHR),
                             args, 0, stream);
}